// Round 2
// 375.074 us; speedup vs baseline: 1.0616x; 1.0616x over previous
//
#include <hip/hip_runtime.h>
#include <hip/hip_bf16.h>

// Problem constants: N=50000, E=1600000, D=3, IN=32, OUT=32, KS=4, K=64, S=8
// Structure: bucket edges by spline base (27 buckets) -> per-bucket MFMA
//   per s: d_s = f[cols] @ W[base+off_s]  (bf16 MFMA, C=0)
//   msg   = sum_s w_s(edge) * d_s        (fp32 scale on MFMA OUTPUT — exact w)
// No Z intermediate; only bf16(f) and bf16(W) roundings (fewer than round 0).
#define NN 50000
#define EE 1600000
#define BPB 64   // blocks per bucket in edge_mfma

typedef __attribute__((ext_vector_type(8))) short  s16x8;   // 8 bf16 (4 VGPRs) — MFMA A/B frag
typedef __attribute__((ext_vector_type(4))) float  f32x4;   // MFMA C/D frag

static __device__ __forceinline__ short f2bs(float x) {
  __hip_bfloat16 h = __float2bfloat16(x);
  short s; __builtin_memcpy(&s, &h, 2); return s;
}

__constant__ int kOffs[8] = {0, 1, 4, 5, 16, 17, 20, 21};

// ---------------------------------------------------------------------------
// Pack W (fp32 [k][i][o], 256 KB) into bf16 MFMA B-fragment layout:
// B[k][c] = W[c>>5][k][c&31],  c = kmat*32+o  (2048 cols, K=32 rows = IN_F).
// Tile t covers cols [t*16, t*16+16) => t = kmat*2 + oh.
// Frag elem (tile t, lane l, j): B[k=(l>>4)*8+j][c=t*16+(l&15)].
// ---------------------------------------------------------------------------
__global__ __launch_bounds__(256) void conv_w(const float* __restrict__ W,
                                              short* __restrict__ Wb) {
  int tid = blockIdx.x * 256 + threadIdx.x;       // 8192 threads
  if (tid >= 128 * 64) return;
  int t = tid >> 6, l = tid & 63;
  int c = t * 16 + (l & 15);
  int k0 = (l >> 4) * 8;
  s16x8 frag;
#pragma unroll
  for (int j = 0; j < 8; ++j) {
    frag[j] = f2bs(W[(c >> 5) * 1024 + (k0 + j) * 32 + (c & 31)]);
  }
  ((s16x8*)Wb)[tid] = frag;
}

// ---------------------------------------------------------------------------
// f fp32 [N][32] -> bf16 [N][32] (3.2 MB, L2-resident; IS the A-fragment).
// ---------------------------------------------------------------------------
__global__ __launch_bounds__(256) void pack_f(const float* __restrict__ f,
                                              short* __restrict__ fbh) {
  int tid = blockIdx.x * 256 + threadIdx.x;
  if (tid >= NN * 32 / 8) return;
  const f32x4* fp = (const f32x4*)f + (size_t)tid * 2;
  f32x4 a = fp[0], b = fp[1];
  s16x8 o;
#pragma unroll
  for (int j = 0; j < 4; ++j) { o[j] = f2bs(a[j]); o[4 + j] = f2bs(b[j]); }
  ((s16x8*)fbh)[tid] = o;
}

// ---------------------------------------------------------------------------
// Pass 1: histogram of bucket q = b0 + 3*b1 + 9*b2 (27 buckets).
// ---------------------------------------------------------------------------
__global__ __launch_bounds__(256) void bucket_hist(const float* __restrict__ pseudo,
                                                   int* __restrict__ hist) {
  __shared__ int lh[27];
  if (threadIdx.x < 27) lh[threadIdx.x] = 0;
  __syncthreads();
  for (int e = blockIdx.x * 256 + threadIdx.x; e < EE; e += gridDim.x * 256) {
    float v0 = pseudo[e * 3 + 0] * 3.0f;
    float v1 = pseudo[e * 3 + 1] * 3.0f;
    float v2 = pseudo[e * 3 + 2] * 3.0f;
    int b0 = (int)fminf(fmaxf(floorf(v0), 0.0f), 2.0f);
    int b1 = (int)fminf(fmaxf(floorf(v1), 0.0f), 2.0f);
    int b2 = (int)fminf(fmaxf(floorf(v2), 0.0f), 2.0f);
    atomicAdd(&lh[b0 + 3 * b1 + 9 * b2], 1);
  }
  __syncthreads();
  if (threadIdx.x < 27) atomicAdd(hist + threadIdx.x, lh[threadIdx.x]);
}

// ---------------------------------------------------------------------------
// Pass 2: exclusive scan of 27 counters (trivial, 1 thread).
// ---------------------------------------------------------------------------
__global__ void bucket_scan(const int* __restrict__ hist,
                            int* __restrict__ bstart,
                            int* __restrict__ cursor) {
  if (threadIdx.x == 0 && blockIdx.x == 0) {
    int run = 0;
    for (int i = 0; i < 27; ++i) { bstart[i] = run; cursor[i] = run; run += hist[i]; }
    bstart[27] = run;
  }
}

// ---------------------------------------------------------------------------
// Pass 3: scatter edges into buckets. Per-block LDS ranks + one global
// cursor atomic per bucket per block => contiguous runs, coalesced writes.
// Writes edata[pos] = (p0,p1,p2, bitcast(col)) and rowB[pos] = row.
// Also counts deg here (one fp32 atomic per edge).
// ---------------------------------------------------------------------------
#define SCPER 8
__global__ __launch_bounds__(256) void bucket_scatter(const float* __restrict__ pseudo,
                                                      const int* __restrict__ ei,
                                                      int* __restrict__ cursor,
                                                      float4* __restrict__ edata,
                                                      int* __restrict__ rowB,
                                                      float* __restrict__ deg) {
  __shared__ int lh[27];
  __shared__ int bb[27];
  if (threadIdx.x < 27) lh[threadIdx.x] = 0;
  __syncthreads();
  const int e0 = blockIdx.x * 256 * SCPER;
  float p0[SCPER], p1[SCPER], p2[SCPER];
  int rk[SCPER], bq[SCPER];
#pragma unroll
  for (int i = 0; i < SCPER; ++i) {
    int e = e0 + i * 256 + threadIdx.x;
    bq[i] = -1;
    if (e < EE) {
      float a0 = pseudo[e * 3 + 0];
      float a1 = pseudo[e * 3 + 1];
      float a2 = pseudo[e * 3 + 2];
      int b0 = (int)fminf(fmaxf(floorf(a0 * 3.0f), 0.0f), 2.0f);
      int b1 = (int)fminf(fmaxf(floorf(a1 * 3.0f), 0.0f), 2.0f);
      int b2 = (int)fminf(fmaxf(floorf(a2 * 3.0f), 0.0f), 2.0f);
      int q = b0 + 3 * b1 + 9 * b2;
      p0[i] = a0; p1[i] = a1; p2[i] = a2;
      rk[i] = atomicAdd(&lh[q], 1);
      bq[i] = q;
    }
  }
  __syncthreads();
  if (threadIdx.x < 27) bb[threadIdx.x] = atomicAdd(&cursor[threadIdx.x], lh[threadIdx.x]);
  __syncthreads();
#pragma unroll
  for (int i = 0; i < SCPER; ++i) {
    if (bq[i] < 0) continue;
    int e = e0 + i * 256 + threadIdx.x;
    int pos = bb[bq[i]] + rk[i];
    int row = ei[e], col = ei[EE + e];
    edata[pos] = make_float4(p0[i], p1[i], p2[i], __int_as_float(col));
    rowB[pos] = row;
    atomicAdd(deg + row, 1.0f);
  }
}

// ---------------------------------------------------------------------------
// Main kernel: per bucket, groups of 16 edges. Per group:
//   A-row m = edge m of group: a[m][k] = bf16(f[col_m][k])  (UNSCALED)
//   per s:  d_s = mfma_16x16x32(A, Wfrag[base+off_s][oh], 0)
//   acc[r] += w_s(edge_of_row_r) * d_s[r]   (fp32 — exact spline weights)
// D layout (m89-verified): col = lane&15 (o within tile), row=(lane>>4)*4+r
// = edge within group. w_s for row-edge fetched via __shfl from lane e
// (lane e computed edge e's weights; invalid edges have w==0 => contribute 0).
// B-frags for the bucket's 8 matrices x 2 col-tiles hoisted into 64 VGPRs.
// ---------------------------------------------------------------------------
__global__ __launch_bounds__(256) void edge_mfma(const float4* __restrict__ edata,
                                                 const int* __restrict__ rowB,
                                                 const short* __restrict__ fbh,
                                                 const short* __restrict__ Wb,
                                                 const int* __restrict__ bstart,
                                                 float* __restrict__ accbuf) {
  const int q   = blockIdx.x / BPB;      // bucket 0..26
  const int sub = blockIdx.x % BPB;
  const int l   = threadIdx.x & 63;
  const int wid = threadIdx.x >> 6;

  const int start = bstart[q];
  const int end   = bstart[q + 1];
  const int nE    = end - start;
  if (nE <= 0) return;
  const int ngroups = (nE + 15) >> 4;

  const int b0 = q % 3, b1 = (q / 3) % 3, b2 = q / 9;
  const int base = b0 + 4 * b1 + 16 * b2;
  const int ko[8] = {0, 1, 4, 5, 16, 17, 20, 21};

  // Hoist the bucket's B fragments: 8 s-matrices x 2 col-tiles (64 VGPRs).
  s16x8 bf[8][2];
#pragma unroll
  for (int s = 0; s < 8; ++s) {
    int kmat = base + ko[s];
#pragma unroll
    for (int oh = 0; oh < 2; ++oh)
      bf[s][oh] = ((const s16x8*)Wb)[(kmat * 2 + oh) * 64 + l];
  }

  const int m   = l & 15;        // edge-in-group this lane's A-row belongs to
  const int och = l & 15;        // D column within tile
  const int eb  = (l >> 4) * 4;  // first D-row edge for this lane's quarter

  for (int g = sub * 4 + wid; g < ngroups; g += BPB * 4) {
    int idx   = start + g * 16 + m;
    bool valid = idx < end;
    int safe  = valid ? idx : start;

    float4 ed = edata[safe];
    int col   = __float_as_int(ed.w);
    int row   = valid ? rowB[safe] : 0;

    // spline weights for this lane's A-edge (shfl source for D-row scaling)
    float f0 = ed.x * 3.0f - (float)b0;
    float f1 = ed.y * 3.0f - (float)b1;
    float f2 = ed.z * 3.0f - (float)b2;
    float g0 = 1.0f - f0, g1 = 1.0f - f1, g2 = 1.0f - f2;
    float vf = valid ? 1.0f : 0.0f;
    g2 *= vf; f2 *= vf;                      // invalid edge => all weights 0
    float w8[8];
    w8[0] = g0 * g1 * g2; w8[1] = f0 * g1 * g2;
    w8[2] = g0 * f1 * g2; w8[3] = f0 * f1 * g2;
    w8[4] = g0 * g1 * f2; w8[5] = f0 * g1 * f2;
    w8[6] = g0 * f1 * f2; w8[7] = f0 * f1 * f2;

    // A-fragment: unscaled bf16 f[col] straight from the packed copy.
    s16x8 af = ((const s16x8*)fbh)[col * 4 + (l >> 4)];

    f32x4 acc0 = {0.f, 0.f, 0.f, 0.f}, acc1 = {0.f, 0.f, 0.f, 0.f};
#pragma unroll
    for (int s = 0; s < 8; ++s) {
      f32x4 d0 = __builtin_amdgcn_mfma_f32_16x16x32_bf16(af, bf[s][0],
                   (f32x4){0.f, 0.f, 0.f, 0.f}, 0, 0, 0);
      f32x4 d1 = __builtin_amdgcn_mfma_f32_16x16x32_bf16(af, bf[s][1],
                   (f32x4){0.f, 0.f, 0.f, 0.f}, 0, 0, 0);
#pragma unroll
      for (int r = 0; r < 4; ++r) {
        float wsr = __shfl(w8[s], eb + r, 64);   // w_s of D-row edge
        acc0[r] += wsr * d0[r];
        acc1[r] += wsr * d1[r];
      }
    }

    // scatter: D row r of quarter p is edge e=(p*4+r); its target row via shfl
#pragma unroll
    for (int r = 0; r < 4; ++r) {
      int rrow = __shfl(row, eb + r, 64);
      atomicAdd(accbuf + (size_t)rrow * 32 + och,      acc0[r]);
      atomicAdd(accbuf + (size_t)rrow * 32 + 16 + och, acc1[r]);
    }
  }
}

// ---------------------------------------------------------------------------
// Spline basis for fallback path.
// ---------------------------------------------------------------------------
static __device__ __forceinline__ void spline_basis(const float* __restrict__ pseudo,
                                                    int e, float w[8], int& base) {
  float v0 = pseudo[e * 3 + 0] * 3.0f;
  float v1 = pseudo[e * 3 + 1] * 3.0f;
  float v2 = pseudo[e * 3 + 2] * 3.0f;
  float b0 = fmaxf(fminf(floorf(v0), 2.0f), 0.0f);
  float b1 = fmaxf(fminf(floorf(v1), 2.0f), 0.0f);
  float b2 = fmaxf(fminf(floorf(v2), 2.0f), 0.0f);
  float f0 = v0 - b0, f1 = v1 - b1, f2 = v2 - b2;
  float g0 = 1.0f - f0, g1 = 1.0f - f1, g2 = 1.0f - f2;
  base = (int)b0 + 4 * (int)b1 + 16 * (int)b2;
  w[0] = g0 * g1 * g2; w[1] = f0 * g1 * g2;
  w[2] = g0 * f1 * g2; w[3] = f0 * f1 * g2;
  w[4] = g0 * g1 * f2; w[5] = f0 * g1 * f2;
  w[6] = g0 * f1 * f2; w[7] = f0 * f1 * f2;
}

// ---------------------------------------------------------------------------
// Fallback (small workspace): direct per-edge compute from f and W.
// ---------------------------------------------------------------------------
__global__ __launch_bounds__(256) void edge_direct(const float* __restrict__ pseudo,
                                                   const int* __restrict__ ei,
                                                   const float* __restrict__ f,
                                                   const float* __restrict__ W,
                                                   float* __restrict__ acc,
                                                   float* __restrict__ deg) {
  const int tid = blockIdx.x * 256 + threadIdx.x;
  const int e = tid >> 5;
  const int o = tid & 31;
  if (e >= EE) return;

  const int row = ei[e];
  const int col = ei[EE + e];

  float w[8]; int base;
  spline_basis(pseudo, e, w, base);

  const float myf = f[col * 32 + o];
  float a = 0.0f;
  for (int i = 0; i < 32; ++i) {
    float fi = __shfl(myf, i, 32);
    float wsum = 0.0f;
#pragma unroll
    for (int s = 0; s < 8; ++s) {
      wsum += w[s] * W[(size_t)(base + kOffs[s]) * 1024 + i * 32 + o];
    }
    a += fi * wsum;
  }

  atomicAdd(acc + (size_t)row * 32 + o, a);
  if (o == 0) atomicAdd(deg + row, 1.0f);
}

// ---------------------------------------------------------------------------
// out[n,o] = acc[n,o] / max(deg[n],1) + bias[o]
// ---------------------------------------------------------------------------
__global__ __launch_bounds__(256) void finalize(const float* __restrict__ acc,
                                                const float* __restrict__ deg,
                                                const float* __restrict__ bias,
                                                float* __restrict__ out) {
  int tid = blockIdx.x * 256 + threadIdx.x;
  if (tid >= NN * 32) return;
  int n = tid >> 5, o = tid & 31;
  float d = fmaxf(deg[n], 1.0f);
  out[tid] = acc[tid] / d + bias[o];
}

extern "C" void kernel_launch(void* const* d_in, const int* in_sizes, int n_in,
                              void* d_out, int out_size, void* d_ws, size_t ws_size,
                              hipStream_t stream) {
  const float* f      = (const float*)d_in[0];
  const float* pseudo = (const float*)d_in[1];
  const float* W      = (const float*)d_in[2];
  const float* bias   = (const float*)d_in[3];
  const int*   ei     = (const int*)d_in[4];
  float* out = (float*)d_out;

  // Workspace layout (~42 MB total)
  constexpr size_t ACC_SZ   = (size_t)NN * 32 * 4;       // 6,400,000
  constexpr size_t DEG_SZ   = (size_t)NN * 4;            //   200,000
  constexpr size_t HIST_OFF = ACC_SZ + DEG_SZ;           // 27 ints (in zeroed pad)
  constexpr size_t ZERO_SZ  = ACC_SZ + DEG_SZ + 256;     // memset covers acc+deg+hist
  constexpr size_t BST_OFF  = ZERO_SZ;                   // 28 ints
  constexpr size_t CUR_OFF  = BST_OFF + 256;             // 27 ints
  constexpr size_t ED_OFF   = CUR_OFF + 256;             // 16B aligned
  constexpr size_t ED_SZ    = (size_t)EE * 16;           // 25,600,000
  constexpr size_t ROW_OFF  = ED_OFF + ED_SZ;
  constexpr size_t ROW_SZ   = (size_t)EE * 4;            //  6,400,000
  constexpr size_t FBH_OFF  = ROW_OFF + ROW_SZ;
  constexpr size_t FBH_SZ   = (size_t)NN * 32 * 2;       //  3,200,000
  constexpr size_t WB_OFF   = FBH_OFF + FBH_SZ;
  constexpr size_t WB_SZ    = 128 * 64 * 8 * 2;          //    131,072
  constexpr size_t TOTAL    = WB_OFF + WB_SZ;            // ~41.9 MB

  char* ws = (char*)d_ws;

  if (ws_size >= TOTAL) {
    float*  acc    = (float*)(ws + 0);
    float*  deg    = (float*)(ws + ACC_SZ);
    int*    hist   = (int*)(ws + HIST_OFF);
    int*    bst    = (int*)(ws + BST_OFF);
    int*    cur    = (int*)(ws + CUR_OFF);
    float4* edata  = (float4*)(ws + ED_OFF);
    int*    rowB   = (int*)(ws + ROW_OFF);
    short*  fbh    = (short*)(ws + FBH_OFF);
    short*  Wb     = (short*)(ws + WB_OFF);

    hipMemsetAsync(ws, 0, ZERO_SZ, stream);
    conv_w<<<32, 256, 0, stream>>>(W, Wb);
    pack_f<<<(NN * 32 / 8 + 255) / 256, 256, 0, stream>>>(f, fbh);
    bucket_hist<<<512, 256, 0, stream>>>(pseudo, hist);
    bucket_scan<<<1, 64, 0, stream>>>(hist, bst, cur);
    bucket_scatter<<<(EE + 256 * SCPER - 1) / (256 * SCPER), 256, 0, stream>>>(
        pseudo, ei, cur, edata, rowB, deg);
    edge_mfma<<<27 * BPB, 256, 0, stream>>>(edata, rowB, fbh, Wb, bst, acc);
    finalize<<<(NN * 32) / 256, 256, 0, stream>>>(acc, deg, bias, out);
  } else {
    float* acc = (float*)ws;
    float* deg = (float*)(ws + ACC_SZ);
    hipMemsetAsync(acc, 0, ACC_SZ + DEG_SZ, stream);
    edge_direct<<<(EE * 32) / 256, 256, 0, stream>>>(pseudo, ei, f, W, acc, deg);
    finalize<<<(NN * 32) / 256, 256, 0, stream>>>(acc, deg, bias, out);
  }
}